// Round 21
// baseline (286.371 us; speedup 1.0000x reference)
//
#include <hip/hip_runtime.h>

typedef unsigned short u16;
typedef __bf16 bf16x8 __attribute__((ext_vector_type(8)));
typedef float f32x4 __attribute__((ext_vector_type(4)));
typedef u16 u16x8 __attribute__((ext_vector_type(8), may_alias));
typedef u16 u16x4 __attribute__((ext_vector_type(4), may_alias));
typedef unsigned int u32x4 __attribute__((ext_vector_type(4)));

#define D_MODEL 1024
#define D_MLP   4096
#define D_HEAD  64
#define N_HEADS 16
#define SEQ     2048
#define BATCH   2
#define BS      (BATCH * SEQ)   // 4096 rows
#define QKV_N   3072
// Q pre-scale: (1/sqrt(64)) * log2(e) so attention works in exp2 domain
#define QSCALE  0.18033688011112042f

__device__ __forceinline__ u16 f2b(float f) {
  unsigned u = __builtin_bit_cast(unsigned, f);
  u += 0x7fffu + ((u >> 16) & 1u);           // round-to-nearest-even
  return (u16)(u >> 16);
}

__device__ __forceinline__ unsigned cvtpk_bf16(float lo, float hi) {
  unsigned r;
  asm("v_cvt_pk_bf16_f32 %0, %1, %2" : "=v"(r) : "v"(lo), "v"(hi));
  return r;
}

__device__ __forceinline__ void gload_lds16(const u16* g, u16* l) {
  __builtin_amdgcn_global_load_lds(
      (const __attribute__((address_space(1))) unsigned int*)g,
      (__attribute__((address_space(3))) unsigned int*)l, 16, 0, 0);
}

// ---------------- fused fp32 -> bf16 convert (ALL inputs, one dispatch) ----------------
__global__ __launch_bounds__(256) void cvt_all(
    const float* __restrict__ x,  const float* __restrict__ wq,
    const float* __restrict__ wk, const float* __restrict__ wv,
    const float* __restrict__ wo, const float* __restrict__ wi,
    const float* __restrict__ wu,
    u16* __restrict__ xb, u16* __restrict__ wqkv, u16* __restrict__ wo_b,
    u16* __restrict__ win_b, u16* __restrict__ wout_b)
{
  const int i = blockIdx.x * 256 + threadIdx.x;   // 0 .. 4194303
  const float* src; u16* dst; int j;
  if (i < 1048576)      { src = x;  dst = xb;              j = i; }
  else if (i < 1310720) { src = wq; dst = wqkv;            j = i - 1048576; }
  else if (i < 1572864) { src = wk; dst = wqkv + 1048576;  j = i - 1310720; }
  else if (i < 1835008) { src = wv; dst = wqkv + 2097152;  j = i - 1572864; }
  else if (i < 2097152) { src = wo; dst = wo_b;            j = i - 1835008; }
  else if (i < 3145728) { src = wi; dst = win_b;           j = i - 2097152; }
  else                  { src = wu; dst = wout_b;          j = i - 3145728; }
  float4 v = ((const float4*)src)[j];
  u16x4 o;
  o[0] = f2b(v.x); o[1] = f2b(v.y); o[2] = f2b(v.z); o[3] = f2b(v.w);
  ((u16x4*)dst)[j] = o;
}

// ---------------- generic bf16 GEMM: C[M,N] = A[M,K] @ B[N,K]^T ----------------
// BM x BN tile (BM in {64,128}, BN in {128,256}), BK=64, 4 waves, 16x16x32 MFMA,
// global_load_lds(16B), XOR slot-swizzle on the GLOBAL source + same XOR on reads
// (proven 2-barrier schedule, unchanged). Per-wave output: (BM/2) x (BN/2).
// BN=256 quadruples MFMA-per-barrier (64/wave/K-step) vs BN=128 — the same
// "bigger tile amortizes the barrier drain" lever proven on attn KVBLK 32->64->128.
// BM=128: 1D grid + XCD/supertile remap (gx cols). BM=64: plain 2D map (MODE1).
// MODE 0: QKV. col<1024: Q*QSCALE -> qk (LD 2048); col<2048: K -> qk; else V -> vt transposed
// MODE 1: o = acc + resid[idx]; outf = o; outb = bf16(o)     (attn out + residual)
// MODE 2: o = relu(acc + bias[col]); outb = bf16(o)          (mlp in)
// MODE 3: split-K=2 (virtual gx=16, z=bx>>3): partial f32 -> outf[z*M*N + idx]
template<int MODE, int BM, int BN>
__global__ __launch_bounds__(256) void gemm_bt(
    const u16* __restrict__ A, const u16* __restrict__ Bw,
    int M, int N, int K,
    u16* __restrict__ outb, float* __restrict__ outf,
    const float* __restrict__ resid, const float* __restrict__ bias,
    u16* __restrict__ vtp, int gx)
{
  constexpr int MI = BM / 32;              // acc row-frags per wave
  constexpr int NI = BN / 32;              // acc col-frags per wave
  __shared__ u16 Asm_[BM * 64];
  __shared__ u16 Bsm_[BN * 64];
  const int t = threadIdx.x;
  const int lane = t & 63;
  const int l15 = lane & 15, l4 = lane >> 4;
  const int w = t >> 6;
  const int wr = w >> 1, wc = w & 1;

  int bx, by;
  if constexpr (BM == 64) {
    bx = blockIdx.x & 7;
    by = blockIdx.x >> 3;
  } else {
    // XCD/supertile remap (gy = 32 rows always; RY=2, CX=4, rh=16)
    const int xcd = blockIdx.x & 7;
    const int local = blockIdx.x >> 3;
    const int rw = gx >> 2;
    const int rx = xcd & 3, ry = xcd >> 2;
    const int c = local >> 4, r0 = local & 15;
    bx = rx * rw + c;
    by = ry * 16 + r0;
  }
  int z = 0;
  if (MODE == 3) { z = bx >> 3; bx &= 7; }
  const int m0 = by * BM;
  const int n0 = bx * BN;
  const int kb = (MODE == 3) ? z * (K >> 1) : 0;
  const int ke = (MODE == 3) ? kb + (K >> 1) : K;

  f32x4 acc[MI][NI] = {};

  for (int k0 = kb; k0 < ke; k0 += 64) {
    __syncthreads();
#pragma unroll
    for (int i = 0; i < BM / 32; ++i) {    // A: BM*8 16B-slots
      int s = i * 256 + t;
      int row = s >> 3;
      int gc = ((s & 7) ^ (row & 7)) << 3; // pre-swizzled global k-chunk
      gload_lds16(A + (size_t)(m0 + row) * K + (k0 + gc),
                  Asm_ + (s & ~63) * 8);   // wave-uniform base
    }
#pragma unroll
    for (int i = 0; i < BN / 32; ++i) {    // B: BN*8 16B-slots
      int s = i * 256 + t;
      int row = s >> 3;
      int gc = ((s & 7) ^ (row & 7)) << 3;
      gload_lds16(Bw + (size_t)(n0 + row) * K + (k0 + gc),
                  Bsm_ + (s & ~63) * 8);
    }
    asm volatile("s_waitcnt vmcnt(0)" ::: "memory");
    __syncthreads();
#pragma unroll
    for (int kk = 0; kk < 2; ++kk) {
      bf16x8 af[MI], bfr[NI];
#pragma unroll
      for (int mi = 0; mi < MI; ++mi) {
        int row = wr * (BM / 2) + mi * 16 + l15;
        int sl2 = (kk * 4 + l4) ^ (row & 7);
        af[mi] = __builtin_bit_cast(bf16x8, *(const u16x8*)(Asm_ + row * 64 + sl2 * 8));
      }
#pragma unroll
      for (int ni = 0; ni < NI; ++ni) {
        int row = wc * (BN / 2) + ni * 16 + l15;
        int sl2 = (kk * 4 + l4) ^ (row & 7);
        bfr[ni] = __builtin_bit_cast(bf16x8, *(const u16x8*)(Bsm_ + row * 64 + sl2 * 8));
      }
#pragma unroll
      for (int mi = 0; mi < MI; ++mi)
#pragma unroll
        for (int ni = 0; ni < NI; ++ni)
          acc[mi][ni] = __builtin_amdgcn_mfma_f32_16x16x32_bf16(af[mi], bfr[ni], acc[mi][ni], 0, 0, 0);
    }
  }

#pragma unroll
  for (int mi = 0; mi < MI; ++mi) {
    int rowb = m0 + wr * (BM / 2) + mi * 16 + l4 * 4;
#pragma unroll
    for (int ni = 0; ni < NI; ++ni) {
      int col = n0 + wc * (BN / 2) + ni * 16 + l15;
#pragma unroll
      for (int r = 0; r < 4; ++r) {
        float v = acc[mi][ni][r];
        int row = rowb + r;
        if (MODE == 0) {
          if (col < 2048) {
            float o = (col < 1024) ? v * QSCALE : v;
            outb[((size_t)row << 11) + col] = f2b(o);
          } else {
            int c2 = col - 2048;                      // c2 = h*64 + d
            size_t vi = (((size_t)((row >> 11) * 1024 + c2)) << 11) + (row & (SEQ - 1));
            vtp[vi] = f2b(v);
          }
        } else if (MODE == 3) {
          outf[(size_t)z * M * N + (size_t)row * N + col] = v;
        } else {
          size_t idx = (size_t)row * N + col;
          if (MODE == 1) {
            float o = v + resid[idx];
            outf[idx] = o;
            outb[idx] = f2b(o);
          } else {
            float o = v + bias[col];
            o = o > 0.f ? o : 0.f;
            outb[idx] = f2b(o);
          }
        }
      }
    }
  }
}

// ---------------- split-K reduce: out = p0 + p1 + resid + bias ----------------
__global__ __launch_bounds__(256) void reduce2_kernel(const float* __restrict__ part,
                                                      const float* __restrict__ resid,
                                                      const float* __restrict__ bias,
                                                      float* __restrict__ out) {
  const int i = blockIdx.x * 256 + threadIdx.x;    // float4 index over BS*1024/4
  float4 a = ((const float4*)part)[i];
  float4 b = ((const float4*)(part + (size_t)BS * D_MODEL))[i];
  float4 r = ((const float4*)resid)[i];
  float4 bi = ((const float4*)bias)[i & 255];      // D_MODEL/4 = 256
  float4 o;
  o.x = a.x + b.x + r.x + bi.x;
  o.y = a.y + b.y + r.y + bi.y;
  o.z = a.z + b.z + r.z + bi.z;
  o.w = a.w + b.w + r.w + bi.w;
  ((float4*)out)[i] = o;
}

// ---------------- causal flash attention, block-shared LDS K/V, KVBLK=128 ----------------
// R18 phase-major version (proven): QK phase reads each K-frag once for both s;
// both softmax chains adjacent; PV phase reads each V-frag once for both s.
__global__ __launch_bounds__(256) void attn_kernel(const u16* __restrict__ qk,
                                                   const u16* __restrict__ vT,
                                                   u16* __restrict__ zb)
{
  __shared__ u16 Kl[2][128 * 64];
  __shared__ u16 Vl[2][64 * 136];
  const int t = threadIdx.x;
  const int w = t >> 6;
  const int lane = t & 63;
  const int l15 = lane & 15, l4 = lane >> 4;
  const int blk = blockIdx.x;
  const int bh = blk & 31;
  const int qb = 15 - (blk >> 5);         // longest blocks first
  const int b = bh >> 4, h = bh & 15;
  const int q0w = qb * 128 + w * 32;
  const int ttmax = qb;                   // diagonal tile for ALL waves

  bf16x8 qf[2][2];
#pragma unroll
  for (int s = 0; s < 2; ++s) {
    const u16* qp = qk + (((size_t)(b * SEQ + q0w + s * 16 + l15)) << 11) + h * 64 + l4 * 8;
    qf[s][0] = __builtin_bit_cast(bf16x8, *(const u16x8*)(qp));
    qf[s][1] = __builtin_bit_cast(bf16x8, *(const u16x8*)(qp + 32));
  }

  const int srow = t >> 3;                      // 0..31
  const int sgc = ((t & 7) ^ (srow & 7)) * 8;   // pre-swizzled k-chunk
  const u16* kgbase = qk + (((size_t)(b * SEQ + srow)) << 11) + 1024 + h * 64 + sgc;
  u16* kldst = &Kl[0][0] + (t & ~63) * 8;       // wave-uniform base (HW adds lane*16B)
  const int vd2 = t >> 2, q4 = t & 3;
  const u16* vgbase = vT + (((size_t)(bh * 64 + vd2)) << 11);

  f32x4 zacc[2][4] = {};
  float m_run[2] = {-1e30f, -1e30f}, l_run[2] = {0.f, 0.f};

  auto stageK = [&](int buf, int tt) {
    const u16* kg = kgbase + ((size_t)tt << 18);    // 128 rows x 2048 u16
    u16* kld = kldst + buf * (128 * 64);
#pragma unroll
    for (int i = 0; i < 4; ++i)
      gload_lds16(kg + ((size_t)i << 16), kld + i * 2048);
  };

  auto compute = [&](int buf, int tt) {
    const bool last = (tt == ttmax);
    f32x4 sf[2][8] = {};
    __builtin_amdgcn_s_setprio(1);
#pragma unroll
    for (int ks = 0; ks < 8; ++ks) {
      const int row = ks * 16 + l15;
#pragma unroll
      for (int kc = 0; kc < 2; ++kc) {
        const int slot = (kc * 4 + l4) ^ (row & 7);
        bf16x8 kf = __builtin_bit_cast(bf16x8,
            *(const u16x8*)&Kl[buf][row * 64 + slot * 8]);
        sf[0][ks] = __builtin_amdgcn_mfma_f32_16x16x32_bf16(kf, qf[0][kc], sf[0][ks], 0, 0, 0);
        sf[1][ks] = __builtin_amdgcn_mfma_f32_16x16x32_bf16(kf, qf[1][kc], sf[1][ks], 0, 0, 0);
      }
    }
    __builtin_amdgcn_s_setprio(0);

    if (last) {
      const int pb = tt * 128 + l4 * 4;
#pragma unroll
      for (int s = 0; s < 2; ++s) {
        const int qq = q0w + s * 16 + l15;
#pragma unroll
        for (int ks = 0; ks < 8; ++ks)
#pragma unroll
          for (int r = 0; r < 4; ++r)
            sf[s][ks][r] = (pb + ks * 16 + r <= qq) ? sf[s][ks][r] : -1e30f;
      }
    }

    float mn[2], sc_[2];
#pragma unroll
    for (int s = 0; s < 2; ++s) {
      float mk[8];
#pragma unroll
      for (int ks = 0; ks < 8; ++ks)
        mk[ks] = fmaxf(fmaxf(sf[s][ks][0], sf[s][ks][1]), fmaxf(sf[s][ks][2], sf[s][ks][3]));
      float mt = fmaxf(fmaxf(fmaxf(mk[0], mk[1]), fmaxf(mk[2], mk[3])),
                       fmaxf(fmaxf(mk[4], mk[5]), fmaxf(mk[6], mk[7])));
      mt = fmaxf(mt, __shfl_xor(mt, 16));
      mt = fmaxf(mt, __shfl_xor(mt, 32));
      mn[s] = fmaxf(m_run[s], mt);
      sc_[s] = __builtin_amdgcn_exp2f(m_run[s] - mn[s]);
      m_run[s] = mn[s];
    }
#pragma unroll
    for (int s = 0; s < 2; ++s) {
      float rs = 0.f;
#pragma unroll
      for (int ks = 0; ks < 8; ++ks)
#pragma unroll
        for (int r = 0; r < 4; ++r) {
          sf[s][ks][r] = __builtin_amdgcn_exp2f(sf[s][ks][r] - mn[s]);   // P in place
          rs += sf[s][ks][r];
        }
      rs += __shfl_xor(rs, 16);
      rs += __shfl_xor(rs, 32);
      l_run[s] = l_run[s] * sc_[s] + rs;
#pragma unroll
      for (int dn = 0; dn < 4; ++dn)
#pragma unroll
        for (int r = 0; r < 4; ++r) zacc[s][dn][r] *= sc_[s];
    }

    bf16x8 pa[2][4];
#pragma unroll
    for (int s = 0; s < 2; ++s)
#pragma unroll
      for (int g = 0; g < 4; ++g) {
        u32x4 pu;
        pu[0] = cvtpk_bf16(sf[s][2 * g][0], sf[s][2 * g][1]);
        pu[1] = cvtpk_bf16(sf[s][2 * g][2], sf[s][2 * g][3]);
        pu[2] = cvtpk_bf16(sf[s][2 * g + 1][0], sf[s][2 * g + 1][1]);
        pu[3] = cvtpk_bf16(sf[s][2 * g + 1][2], sf[s][2 * g + 1][3]);
        pa[s][g] = __builtin_bit_cast(bf16x8, pu);
      }

    __builtin_amdgcn_s_setprio(1);
#pragma unroll
    for (int g = 0; g < 4; ++g)
#pragma unroll
      for (int dn = 0; dn < 4; ++dn) {
        bf16x8 vfr = __builtin_bit_cast(bf16x8,
            *(const u16x8*)&Vl[buf][(dn * 16 + l15) * 136 + g * 32 + l4 * 8]);
        zacc[0][dn] = __builtin_amdgcn_mfma_f32_16x16x32_bf16(vfr, pa[0][g], zacc[0][dn], 0, 0, 0);
        zacc[1][dn] = __builtin_amdgcn_mfma_f32_16x16x32_bf16(vfr, pa[1][g], zacc[1][dn], 0, 0, 0);
      }
    __builtin_amdgcn_s_setprio(0);
  };

  stageK(0, 0);
  {
#pragma unroll
    for (int g = 0; g < 4; ++g) {
      const u16* vg = vgbase + g * 32 + q4 * 4;
      u16x4 lo = *(const u16x4*)(vg);
      u16x4 hi = *(const u16x4*)(vg + 16);
      *(u16x8*)&Vl[0][vd2 * 136 + g * 32 + q4 * 8] =
          __builtin_shufflevector(lo, hi, 0, 1, 2, 3, 4, 5, 6, 7);
    }
  }
  asm volatile("s_waitcnt vmcnt(0)" ::: "memory");
  __syncthreads();

  int cur = 0;
  for (int tt = 0; tt <= ttmax; ++tt) {
    const bool more = tt < ttmax;
    u16x4 lo[4], hi[4];
    if (more) {
      stageK(cur ^ 1, tt + 1);
#pragma unroll
      for (int g = 0; g < 4; ++g) {
        const u16* vg = vgbase + (tt + 1) * 128 + g * 32 + q4 * 4;
        lo[g] = *(const u16x4*)(vg);
        hi[g] = *(const u16x4*)(vg + 16);
      }
    }
    compute(cur, tt);
    if (more) {
#pragma unroll
      for (int g = 0; g < 4; ++g)
        *(u16x8*)&Vl[cur ^ 1][vd2 * 136 + g * 32 + q4 * 8] =
            __builtin_shufflevector(lo[g], hi[g], 0, 1, 2, 3, 4, 5, 6, 7);
    }
    asm volatile("s_waitcnt vmcnt(0)" ::: "memory");
    __syncthreads();
    cur ^= 1;
  }

#pragma unroll
  for (int s = 0; s < 2; ++s) {
    const float inv = 1.f / l_run[s];
    const size_t rowoff = ((size_t)(b * SEQ + q0w + s * 16 + l15)) * D_MODEL + h * 64 + l4 * 4;
#pragma unroll
    for (int dn = 0; dn < 4; ++dn) {
      u16x4 o;
#pragma unroll
      for (int r = 0; r < 4; ++r) o[r] = f2b(zacc[s][dn][r] * inv);
      *(u16x4*)(zb + rowoff + dn * 16) = o;
    }
  }
}

// ---------------- launch ----------------
extern "C" void kernel_launch(void* const* d_in, const int* in_sizes, int n_in,
                              void* d_out, int out_size, void* d_ws, size_t ws_size,
                              hipStream_t stream) {
  const float* x     = (const float*)d_in[0];
  const float* W_K   = (const float*)d_in[1];
  const float* W_Q   = (const float*)d_in[2];
  const float* W_V   = (const float*)d_in[3];
  const float* W_O   = (const float*)d_in[4];
  const float* W_in  = (const float*)d_in[5];
  const float* b_in  = (const float*)d_in[6];
  const float* W_out = (const float*)d_in[7];
  const float* b_out = (const float*)d_in[8];
  float* out = (float*)d_out;

  // Workspace: live-at-MODE3 buffers first, then the dead pool hosting split-K partials.
  char* p = (char*)d_ws;
  float* x1f  = (float*)p;         p += (size_t)BS * D_MODEL * 4;
  u16* hb     = (u16*)p;           p += (size_t)BS * D_MLP * 2;
  u16* wout_b = (u16*)p;           p += (size_t)D_MODEL * D_MLP * 2;
  u16* xb     = (u16*)p;           p += (size_t)BS * D_MODEL * 2;
  u16* wqkv   = (u16*)p;           p += (size_t)QKV_N * D_MODEL * 2;
  u16* wo_b   = (u16*)p;           p += (size_t)D_MODEL * D_MODEL * 2;
  u16* win_b  = (u16*)p;           p += (size_t)D_MLP * D_MODEL * 2;
  u16* qk     = (u16*)p;           p += (size_t)BS * 2048 * 2;          // Q|K, LD 2048
  u16* vt     = (u16*)p;           p += (size_t)BATCH * 1024 * SEQ * 2; // V^T per (b,h,d)
  u16* zb     = (u16*)p;           p += (size_t)BS * D_MODEL * 2;
  u16* x1b    = (u16*)p;           p += (size_t)BS * D_MODEL * 2;
  float* part = (float*)xb;        // 2 x BS x 1024 f32 = 33.6 MB over dead xb..win_b

  // all fp32->bf16 conversions in ONE dispatch (4.19M float4 units)
  cvt_all<<<dim3(16384), 256, 0, stream>>>(
      x, W_Q, W_K, W_V, W_O, W_in, W_out, xb, wqkv, wo_b, win_b, wout_b);

  // QKV projection: 128x256 tile -> 32 rows x 12 cols = 384 blocks (gx=12)
  gemm_bt<0, 128, 256><<<dim3(384), 256, 0, stream>>>(
      xb, wqkv, BS, QKV_N, D_MODEL, qk, nullptr, nullptr, nullptr, vt, 12);

  // attention: 32 bh x 16 q-blocks (128 rows each), KVBLK=128, phase-major compute
  attn_kernel<<<dim3(512), 256, 0, stream>>>(qk, vt, zb);

  // attn out + residual: z @ W_O^T + x -> x1 (f32 + bf16). BM=64 -> 512 blocks, 2/CU.
  gemm_bt<1, 64, 128><<<dim3(512), 256, 0, stream>>>(
      zb, wo_b, BS, D_MODEL, D_MODEL, x1b, x1f, x, nullptr, nullptr, 8);

  // MLP in: relu(x1 @ W_in^T + b_in) -> h. 128x256 tile -> 32 x 16 = 512 blocks (gx=16)
  gemm_bt<2, 128, 256><<<dim3(512), 256, 0, stream>>>(
      x1b, win_b, BS, D_MLP, D_MODEL, hb, nullptr, nullptr, b_in, nullptr, 16);

  // MLP out, split-K=2 (virtual gx=16): h @ W_out^T -> part[z]
  gemm_bt<3, 128, 128><<<dim3(16 * 32), 256, 0, stream>>>(
      hb, wout_b, BS, D_MODEL, D_MLP, nullptr, part, nullptr, nullptr, nullptr, 16);

  // out = part0 + part1 + x1 + b_out
  reduce2_kernel<<<dim3(BS * D_MODEL / 4 / 256), 256, 0, stream>>>(part, x1f, b_out, out);
}

// Round 22
// 236.438 us; speedup vs baseline: 1.2112x; 1.2112x over previous
//
#include <hip/hip_runtime.h>

typedef unsigned short u16;
typedef __bf16 bf16x8 __attribute__((ext_vector_type(8)));
typedef float f32x4 __attribute__((ext_vector_type(4)));
typedef u16 u16x8 __attribute__((ext_vector_type(8), may_alias));
typedef u16 u16x4 __attribute__((ext_vector_type(4), may_alias));
typedef unsigned int u32x4 __attribute__((ext_vector_type(4)));

#define D_MODEL 1024
#define D_MLP   4096
#define D_HEAD  64
#define N_HEADS 16
#define SEQ     2048
#define BATCH   2
#define BS      (BATCH * SEQ)   // 4096 rows
#define QKV_N   3072
// Q pre-scale: (1/sqrt(64)) * log2(e) so attention works in exp2 domain
#define QSCALE  0.18033688011112042f

__device__ __forceinline__ u16 f2b(float f) {
  unsigned u = __builtin_bit_cast(unsigned, f);
  u += 0x7fffu + ((u >> 16) & 1u);           // round-to-nearest-even
  return (u16)(u >> 16);
}

__device__ __forceinline__ unsigned cvtpk_bf16(float lo, float hi) {
  unsigned r;
  asm("v_cvt_pk_bf16_f32 %0, %1, %2" : "=v"(r) : "v"(lo), "v"(hi));
  return r;
}

__device__ __forceinline__ void gload_lds16(const u16* g, u16* l) {
  __builtin_amdgcn_global_load_lds(
      (const __attribute__((address_space(1))) unsigned int*)g,
      (__attribute__((address_space(3))) unsigned int*)l, 16, 0, 0);
}

// ---------------- fused fp32 -> bf16 convert (ALL inputs, one dispatch) ----------------
__global__ __launch_bounds__(256) void cvt_all(
    const float* __restrict__ x,  const float* __restrict__ wq,
    const float* __restrict__ wk, const float* __restrict__ wv,
    const float* __restrict__ wo, const float* __restrict__ wi,
    const float* __restrict__ wu,
    u16* __restrict__ xb, u16* __restrict__ wqkv, u16* __restrict__ wo_b,
    u16* __restrict__ win_b, u16* __restrict__ wout_b)
{
  const int i = blockIdx.x * 256 + threadIdx.x;   // 0 .. 4194303
  const float* src; u16* dst; int j;
  if (i < 1048576)      { src = x;  dst = xb;              j = i; }
  else if (i < 1310720) { src = wq; dst = wqkv;            j = i - 1048576; }
  else if (i < 1572864) { src = wk; dst = wqkv + 1048576;  j = i - 1310720; }
  else if (i < 1835008) { src = wv; dst = wqkv + 2097152;  j = i - 1572864; }
  else if (i < 2097152) { src = wo; dst = wo_b;            j = i - 1835008; }
  else if (i < 3145728) { src = wi; dst = win_b;           j = i - 2097152; }
  else                  { src = wu; dst = wout_b;          j = i - 3145728; }
  float4 v = ((const float4*)src)[j];
  u16x4 o;
  o[0] = f2b(v.x); o[1] = f2b(v.y); o[2] = f2b(v.z); o[3] = f2b(v.w);
  ((u16x4*)dst)[j] = o;
}

// ---------------- generic bf16 GEMM: C[M,N] = A[M,K] @ B[N,K]^T ----------------
// BM x 128 tile (BM = 128 or 64), BK=64, 4 waves, 16x16x32 MFMA, global_load_lds(16B),
// XOR slot-swizzle applied to the GLOBAL source (LDS stays linear) + same XOR on reads.
// BM=128: 1D grid + XCD/supertile remap. BM=64: plain 2D map (2x blocks for MODE1).
// MODE 0: QKV. col<1024: Q*QSCALE -> qk (LD 2048); col<2048: K -> qk; else V -> vt transposed
// MODE 1: o = acc + resid[idx]; outf = o; outb = bf16(o)     (attn out + residual)
// MODE 2: o = relu(acc + bias[col]); outb = bf16(o)          (mlp in)
// MODE 3: split-K=2 (virtual gx=16, z=bx>>3): partial f32 -> outf[z*M*N + idx]
template<int MODE, int BM>
__global__ __launch_bounds__(256) void gemm_bt(
    const u16* __restrict__ A, const u16* __restrict__ Bw,
    int M, int N, int K,
    u16* __restrict__ outb, float* __restrict__ outf,
    const float* __restrict__ resid, const float* __restrict__ bias,
    u16* __restrict__ vtp, int gx)
{
  constexpr int MI = BM / 32;              // acc row-frags per wave (4 or 2)
  __shared__ u16 Asm_[BM * 64];
  __shared__ u16 Bsm_[128 * 64];
  const int t = threadIdx.x;
  const int lane = t & 63;
  const int l15 = lane & 15, l4 = lane >> 4;
  const int w = t >> 6;
  const int wr = w >> 1, wc = w & 1;

  int bx, by;
  if constexpr (BM == 64) {
    bx = blockIdx.x & 7;
    by = blockIdx.x >> 3;
  } else {
    // XCD/supertile remap (gy = 32 rows always; RY=2, CX=4, rh=16)
    const int xcd = blockIdx.x & 7;
    const int local = blockIdx.x >> 3;
    const int rw = gx >> 2;
    const int rx = xcd & 3, ry = xcd >> 2;
    const int c = local >> 4, r0 = local & 15;
    bx = rx * rw + c;
    by = ry * 16 + r0;
  }
  int z = 0;
  if (MODE == 3) { z = bx >> 3; bx &= 7; }
  const int m0 = by * BM;
  const int n0 = bx * 128;
  const int kb = (MODE == 3) ? z * (K >> 1) : 0;
  const int ke = (MODE == 3) ? kb + (K >> 1) : K;

  f32x4 acc[MI][4] = {};

  for (int k0 = kb; k0 < ke; k0 += 64) {
    __syncthreads();
#pragma unroll
    for (int i = 0; i < 4; ++i) {
      int s = i * 256 + t;                 // 16B slot index 0..1023
      int row = s >> 3;
      int sl = s & 7;
      int gc = ((sl ^ (row & 7)) << 3);    // pre-swizzled global k-chunk
      const u16* gb = Bw + (size_t)(n0 + row) * K + (k0 + gc);
      u16* lb = Bsm_ + (i * 256 + (t & ~63)) * 8;
      if (BM == 128 || i < 2) {            // A has BM rows only
        const u16* ga = A + (size_t)(m0 + row) * K + (k0 + gc);
        u16* la = Asm_ + (i * 256 + (t & ~63)) * 8;   // wave-uniform base
        gload_lds16(ga, la);
      }
      gload_lds16(gb, lb);
    }
    asm volatile("s_waitcnt vmcnt(0)" ::: "memory");
    __syncthreads();
#pragma unroll
    for (int kk = 0; kk < 2; ++kk) {
      bf16x8 af[MI], bfr[4];
#pragma unroll
      for (int mi = 0; mi < MI; ++mi) {
        int row = wr * (BM / 2) + mi * 16 + l15;
        int sl2 = (kk * 4 + l4) ^ (row & 7);
        u16x8 ua = *(const u16x8*)(Asm_ + row * 64 + sl2 * 8);
        af[mi] = __builtin_bit_cast(bf16x8, ua);
      }
#pragma unroll
      for (int ni = 0; ni < 4; ++ni) {
        int row = wc * 64 + ni * 16 + l15;
        int sl2 = (kk * 4 + l4) ^ (row & 7);
        u16x8 ub = *(const u16x8*)(Bsm_ + row * 64 + sl2 * 8);
        bfr[ni] = __builtin_bit_cast(bf16x8, ub);
      }
#pragma unroll
      for (int mi = 0; mi < MI; ++mi)
#pragma unroll
        for (int ni = 0; ni < 4; ++ni)
          acc[mi][ni] = __builtin_amdgcn_mfma_f32_16x16x32_bf16(af[mi], bfr[ni], acc[mi][ni], 0, 0, 0);
    }
  }

#pragma unroll
  for (int mi = 0; mi < MI; ++mi) {
    int rowb = m0 + wr * (BM / 2) + mi * 16 + l4 * 4;
#pragma unroll
    for (int ni = 0; ni < 4; ++ni) {
      int col = n0 + wc * 64 + ni * 16 + l15;
#pragma unroll
      for (int r = 0; r < 4; ++r) {
        float v = acc[mi][ni][r];
        int row = rowb + r;
        if (MODE == 0) {
          if (col < 2048) {
            float o = (col < 1024) ? v * QSCALE : v;
            outb[((size_t)row << 11) + col] = f2b(o);
          } else {
            int c2 = col - 2048;                      // c2 = h*64 + d
            size_t vi = (((size_t)((row >> 11) * 1024 + c2)) << 11) + (row & (SEQ - 1));
            vtp[vi] = f2b(v);
          }
        } else if (MODE == 3) {
          outf[(size_t)z * M * N + (size_t)row * N + col] = v;
        } else {
          size_t idx = (size_t)row * N + col;
          if (MODE == 1) {
            float o = v + resid[idx];
            outf[idx] = o;
            outb[idx] = f2b(o);
          } else {
            float o = v + bias[col];
            o = o > 0.f ? o : 0.f;
            outb[idx] = f2b(o);
          }
        }
      }
    }
  }
}

// ---------------- split-K reduce: out = p0 + p1 + resid + bias ----------------
__global__ __launch_bounds__(256) void reduce2_kernel(const float* __restrict__ part,
                                                      const float* __restrict__ resid,
                                                      const float* __restrict__ bias,
                                                      float* __restrict__ out) {
  const int i = blockIdx.x * 256 + threadIdx.x;    // float4 index over BS*1024/4
  float4 a = ((const float4*)part)[i];
  float4 b = ((const float4*)(part + (size_t)BS * D_MODEL))[i];
  float4 r = ((const float4*)resid)[i];
  float4 bi = ((const float4*)bias)[i & 255];      // D_MODEL/4 = 256
  float4 o;
  o.x = a.x + b.x + r.x + bi.x;
  o.y = a.y + b.y + r.y + bi.y;
  o.z = a.z + b.z + r.z + bi.z;
  o.w = a.w + b.w + r.w + bi.w;
  ((float4*)out)[i] = o;
}

// ---------------- causal flash attention, block-shared LDS K/V, KVBLK=128 ----------------
// R13 geometry (proven 62 us) with PHASE-MAJOR compute: QK phase reads each K-frag
// ONCE for both q-subtiles (s=0,1); both softmax chains run adjacently (independent
// -> scheduler overlaps their shfl/exp2 latencies); PV phase reads each V-frag ONCE
// for both s. Halves LDS reads per tile (64 -> 32 ds_read_b128). exp2 overwrites sf
// in place to cap VGPR. All MFMAs the proven builtin; no sync-structure change.
__global__ __launch_bounds__(256) void attn_kernel(const u16* __restrict__ qk,
                                                   const u16* __restrict__ vT,
                                                   u16* __restrict__ zb)
{
  __shared__ u16 Kl[2][128 * 64];
  __shared__ u16 Vl[2][64 * 136];
  const int t = threadIdx.x;
  const int w = t >> 6;
  const int lane = t & 63;
  const int l15 = lane & 15, l4 = lane >> 4;
  const int blk = blockIdx.x;
  const int bh = blk & 31;
  const int qb = 15 - (blk >> 5);         // longest blocks first
  const int b = bh >> 4, h = bh & 15;
  const int q0w = qb * 128 + w * 32;
  const int ttmax = qb;                   // diagonal tile for ALL waves

  // Q fragments: qf[sub][kc] for q rows q0w + sub*16 + l15
  bf16x8 qf[2][2];
#pragma unroll
  for (int s = 0; s < 2; ++s) {
    const u16* qp = qk + (((size_t)(b * SEQ + q0w + s * 16 + l15)) << 11) + h * 64 + l4 * 8;
    qf[s][0] = __builtin_bit_cast(bf16x8, *(const u16x8*)(qp));
    qf[s][1] = __builtin_bit_cast(bf16x8, *(const u16x8*)(qp + 32));
  }

  // K staging: thread t -> tile rows srow + 32*i (4 shots), slot t&7
  const int srow = t >> 3;                      // 0..31
  const int sgc = ((t & 7) ^ (srow & 7)) * 8;   // pre-swizzled k-chunk
  const u16* kgbase = qk + (((size_t)(b * SEQ + srow)) << 11) + 1024 + h * 64 + sgc;
  u16* kldst = &Kl[0][0] + (t & ~63) * 8;       // wave-uniform base (HW adds lane*16B)
  // V staging (permuted): thread t -> row vd2 (0..63), quad q4 (0..3), 4 g-slots
  const int vd2 = t >> 2, q4 = t & 3;
  const u16* vgbase = vT + (((size_t)(bh * 64 + vd2)) << 11);

  f32x4 zacc[2][4] = {};
  float m_run[2] = {-1e30f, -1e30f}, l_run[2] = {0.f, 0.f};

  auto stageK = [&](int buf, int tt) {
    const u16* kg = kgbase + ((size_t)tt << 18);    // 128 rows x 2048 u16
    u16* kld = kldst + buf * (128 * 64);
#pragma unroll
    for (int i = 0; i < 4; ++i)
      gload_lds16(kg + ((size_t)i << 16), kld + i * 2048);
  };

  auto compute = [&](int buf, int tt) {
    const bool last = (tt == ttmax);
    // ---- QK phase: each K-frag read once, feeds both s ----
    f32x4 sf[2][8] = {};
    __builtin_amdgcn_s_setprio(1);
#pragma unroll
    for (int ks = 0; ks < 8; ++ks) {
      const int row = ks * 16 + l15;
#pragma unroll
      for (int kc = 0; kc < 2; ++kc) {
        const int slot = (kc * 4 + l4) ^ (row & 7);
        bf16x8 kf = __builtin_bit_cast(bf16x8,
            *(const u16x8*)&Kl[buf][row * 64 + slot * 8]);
        sf[0][ks] = __builtin_amdgcn_mfma_f32_16x16x32_bf16(kf, qf[0][kc], sf[0][ks], 0, 0, 0);
        sf[1][ks] = __builtin_amdgcn_mfma_f32_16x16x32_bf16(kf, qf[1][kc], sf[1][ks], 0, 0, 0);
      }
    }
    __builtin_amdgcn_s_setprio(0);

    if (last) {
      const int pb = tt * 128 + l4 * 4;
#pragma unroll
      for (int s = 0; s < 2; ++s) {
        const int qq = q0w + s * 16 + l15;
#pragma unroll
        for (int ks = 0; ks < 8; ++ks)
#pragma unroll
          for (int r = 0; r < 4; ++r)
            sf[s][ks][r] = (pb + ks * 16 + r <= qq) ? sf[s][ks][r] : -1e30f;
      }
    }

    // ---- softmax phase: both s chains adjacent (independent -> overlap) ----
    float mn[2], sc_[2];
#pragma unroll
    for (int s = 0; s < 2; ++s) {
      float mk[8];
#pragma unroll
      for (int ks = 0; ks < 8; ++ks)
        mk[ks] = fmaxf(fmaxf(sf[s][ks][0], sf[s][ks][1]), fmaxf(sf[s][ks][2], sf[s][ks][3]));
      float mt = fmaxf(fmaxf(fmaxf(mk[0], mk[1]), fmaxf(mk[2], mk[3])),
                       fmaxf(fmaxf(mk[4], mk[5]), fmaxf(mk[6], mk[7])));
      mt = fmaxf(mt, __shfl_xor(mt, 16));
      mt = fmaxf(mt, __shfl_xor(mt, 32));
      mn[s] = fmaxf(m_run[s], mt);
      sc_[s] = __builtin_amdgcn_exp2f(m_run[s] - mn[s]);
      m_run[s] = mn[s];
    }
#pragma unroll
    for (int s = 0; s < 2; ++s) {
      float rs = 0.f;
#pragma unroll
      for (int ks = 0; ks < 8; ++ks)
#pragma unroll
        for (int r = 0; r < 4; ++r) {
          sf[s][ks][r] = __builtin_amdgcn_exp2f(sf[s][ks][r] - mn[s]);   // P in place
          rs += sf[s][ks][r];
        }
      rs += __shfl_xor(rs, 16);
      rs += __shfl_xor(rs, 32);
      l_run[s] = l_run[s] * sc_[s] + rs;
#pragma unroll
      for (int dn = 0; dn < 4; ++dn)
#pragma unroll
        for (int r = 0; r < 4; ++r) zacc[s][dn][r] *= sc_[s];
    }

    // ---- pack P (both s) ----
    bf16x8 pa[2][4];
#pragma unroll
    for (int s = 0; s < 2; ++s)
#pragma unroll
      for (int g = 0; g < 4; ++g) {
        u32x4 pu;
        pu[0] = cvtpk_bf16(sf[s][2 * g][0], sf[s][2 * g][1]);
        pu[1] = cvtpk_bf16(sf[s][2 * g][2], sf[s][2 * g][3]);
        pu[2] = cvtpk_bf16(sf[s][2 * g + 1][0], sf[s][2 * g + 1][1]);
        pu[3] = cvtpk_bf16(sf[s][2 * g + 1][2], sf[s][2 * g + 1][3]);
        pa[s][g] = __builtin_bit_cast(bf16x8, pu);
      }

    // ---- PV phase: each V-frag read once, feeds both s ----
    __builtin_amdgcn_s_setprio(1);
#pragma unroll
    for (int g = 0; g < 4; ++g)
#pragma unroll
      for (int dn = 0; dn < 4; ++dn) {
        bf16x8 vfr = __builtin_bit_cast(bf16x8,
            *(const u16x8*)&Vl[buf][(dn * 16 + l15) * 136 + g * 32 + l4 * 8]);
        zacc[0][dn] = __builtin_amdgcn_mfma_f32_16x16x32_bf16(vfr, pa[0][g], zacc[0][dn], 0, 0, 0);
        zacc[1][dn] = __builtin_amdgcn_mfma_f32_16x16x32_bf16(vfr, pa[1][g], zacc[1][dn], 0, 0, 0);
      }
    __builtin_amdgcn_s_setprio(0);
  };

  // prologue: stage tile 0 (K: 4 shots; V: 4 permuted 16B writes)
  stageK(0, 0);
  {
#pragma unroll
    for (int g = 0; g < 4; ++g) {
      const u16* vg = vgbase + g * 32 + q4 * 4;
      u16x4 lo = *(const u16x4*)(vg);
      u16x4 hi = *(const u16x4*)(vg + 16);
      *(u16x8*)&Vl[0][vd2 * 136 + g * 32 + q4 * 8] =
          __builtin_shufflevector(lo, hi, 0, 1, 2, 3, 4, 5, 6, 7);
    }
  }
  asm volatile("s_waitcnt vmcnt(0)" ::: "memory");
  __syncthreads();

  int cur = 0;
  for (int tt = 0; tt <= ttmax; ++tt) {
    const bool more = tt < ttmax;
    u16x4 lo[4], hi[4];
    if (more) {
      stageK(cur ^ 1, tt + 1);
#pragma unroll
      for (int g = 0; g < 4; ++g) {
        const u16* vg = vgbase + (tt + 1) * 128 + g * 32 + q4 * 4;
        lo[g] = *(const u16x4*)(vg);
        hi[g] = *(const u16x4*)(vg + 16);
      }
    }
    compute(cur, tt);
    if (more) {
#pragma unroll
      for (int g = 0; g < 4; ++g)
        *(u16x8*)&Vl[cur ^ 1][vd2 * 136 + g * 32 + q4 * 8] =
            __builtin_shufflevector(lo[g], hi[g], 0, 1, 2, 3, 4, 5, 6, 7);
    }
    asm volatile("s_waitcnt vmcnt(0)" ::: "memory");
    __syncthreads();
    cur ^= 1;
  }

  // epilogue: z[q][h*64 + d], stats uniform per q
#pragma unroll
  for (int s = 0; s < 2; ++s) {
    const float inv = 1.f / l_run[s];
    const size_t rowoff = ((size_t)(b * SEQ + q0w + s * 16 + l15)) * D_MODEL + h * 64 + l4 * 4;
#pragma unroll
    for (int dn = 0; dn < 4; ++dn) {
      u16x4 o;
#pragma unroll
      for (int r = 0; r < 4; ++r) o[r] = f2b(zacc[s][dn][r] * inv);
      *(u16x4*)(zb + rowoff + dn * 16) = o;
    }
  }
}

// ---------------- launch ----------------
extern "C" void kernel_launch(void* const* d_in, const int* in_sizes, int n_in,
                              void* d_out, int out_size, void* d_ws, size_t ws_size,
                              hipStream_t stream) {
  const float* x     = (const float*)d_in[0];
  const float* W_K   = (const float*)d_in[1];
  const float* W_Q   = (const float*)d_in[2];
  const float* W_V   = (const float*)d_in[3];
  const float* W_O   = (const float*)d_in[4];
  const float* W_in  = (const float*)d_in[5];
  const float* b_in  = (const float*)d_in[6];
  const float* W_out = (const float*)d_in[7];
  const float* b_out = (const float*)d_in[8];
  float* out = (float*)d_out;

  // Workspace: live-at-MODE3 buffers first, then the dead pool hosting split-K partials.
  char* p = (char*)d_ws;
  float* x1f  = (float*)p;         p += (size_t)BS * D_MODEL * 4;
  u16* hb     = (u16*)p;           p += (size_t)BS * D_MLP * 2;
  u16* wout_b = (u16*)p;           p += (size_t)D_MODEL * D_MLP * 2;
  u16* xb     = (u16*)p;           p += (size_t)BS * D_MODEL * 2;
  u16* wqkv   = (u16*)p;           p += (size_t)QKV_N * D_MODEL * 2;
  u16* wo_b   = (u16*)p;           p += (size_t)D_MODEL * D_MODEL * 2;
  u16* win_b  = (u16*)p;           p += (size_t)D_MLP * D_MODEL * 2;
  u16* qk     = (u16*)p;           p += (size_t)BS * 2048 * 2;          // Q|K, LD 2048
  u16* vt     = (u16*)p;           p += (size_t)BATCH * 1024 * SEQ * 2; // V^T per (b,h,d)
  u16* zb     = (u16*)p;           p += (size_t)BS * D_MODEL * 2;
  u16* x1b    = (u16*)p;           p += (size_t)BS * D_MODEL * 2;
  float* part = (float*)xb;        // 2 x BS x 1024 f32 = 33.6 MB over dead xb..win_b

  // all fp32->bf16 conversions in ONE dispatch (4.19M float4 units)
  cvt_all<<<dim3(16384), 256, 0, stream>>>(
      x, W_Q, W_K, W_V, W_O, W_in, W_out, xb, wqkv, wo_b, win_b, wout_b);

  // QKV projection: [4096,1024] @ [3072,1024]^T -> qk (Q prescaled | K) + vt (V^T)
  gemm_bt<0, 128><<<dim3(24 * 32), 256, 0, stream>>>(
      xb, wqkv, BS, QKV_N, D_MODEL, qk, nullptr, nullptr, nullptr, vt, 24);

  // attention: 32 bh x 16 q-blocks (128 rows each), KVBLK=128, phase-major compute
  attn_kernel<<<dim3(512), 256, 0, stream>>>(qk, vt, zb);

  // attn out + residual: z @ W_O^T + x -> x1 (f32 + bf16). BM=64 -> 512 blocks, 2/CU.
  gemm_bt<1, 64><<<dim3(512), 256, 0, stream>>>(
      zb, wo_b, BS, D_MODEL, D_MODEL, x1b, x1f, x, nullptr, nullptr, 8);

  // MLP in: relu(x1 @ W_in^T + b_in) -> h
  gemm_bt<2, 128><<<dim3(32 * 32), 256, 0, stream>>>(
      x1b, win_b, BS, D_MLP, D_MODEL, hb, nullptr, nullptr, b_in, nullptr, 32);

  // MLP out, split-K=2 (virtual gx=16): h @ W_out^T -> part[z]
  gemm_bt<3, 128><<<dim3(16 * 32), 256, 0, stream>>>(
      hb, wout_b, BS, D_MODEL, D_MLP, nullptr, part, nullptr, nullptr, nullptr, 16);

  // out = part0 + part1 + x1 + b_out
  reduce2_kernel<<<dim3(BS * D_MODEL / 4 / 256), 256, 0, stream>>>(part, x1f, b_out, out);
}